// Round 2
// baseline (72.007 us; speedup 1.0000x reference)
//
#include <hip/hip_runtime.h>

// db4 decomposition low-pass
static constexpr float H0 = -0.010597401784997278f;
static constexpr float H1 =  0.032883011666982945f;
static constexpr float H2 =  0.030841381835986965f;
static constexpr float H3 = -0.18703481171888114f;
static constexpr float H4 = -0.02798376941698385f;
static constexpr float H5 =  0.6308807679295904f;
static constexpr float H6 =  0.7148465705525415f;
static constexpr float H7 =  0.23037781330885523f;

// Correlation weights with the per-level 0.5 folded in (exact pow2 scale).
static constexpr float W0[8] = { 0.5f*H0,  0.5f*H1,  0.5f*H2,  0.5f*H3,
                                 0.5f*H4,  0.5f*H5,  0.5f*H6,  0.5f*H7 };
static constexpr float W1[8] = {-0.5f*H7,  0.5f*H6, -0.5f*H5,  0.5f*H4,
                                -0.5f*H3,  0.5f*H2, -0.5f*H1,  0.5f*H0 };

constexpr int T     = 4096;
constexpr int GMASK = 1023;   // granules per row - 1
constexpr int BANDF = 5120;   // padded floats per band (pad 1 granule per 4)
constexpr int RPB   = 8;      // rows per persistent block

static __device__ __forceinline__ int gaddr(int g) { return (g << 2) + ((g >> 2) << 2); }

template <int D, int NG>
static __device__ __forceinline__ void level(const float* __restrict__ lo_buf,
                                             const float* __restrict__ hi_buf,
                                             int g0, float res[16])
{
    float wl[NG * 4], wh[NG * 4];
#pragma unroll
    for (int j = 0; j < NG; ++j) {
        const int g = (g0 - D + j) & GMASK;
        const int a = gaddr(g);
        const float4 vl = *(const float4*)(lo_buf + a);
        const float4 vh = *(const float4*)(hi_buf + a);
        wl[4 * j + 0] = vl.x; wl[4 * j + 1] = vl.y; wl[4 * j + 2] = vl.z; wl[4 * j + 3] = vl.w;
        wh[4 * j + 0] = vh.x; wh[4 * j + 1] = vh.y; wh[4 * j + 2] = vh.z; wh[4 * j + 3] = vh.w;
    }
#pragma unroll
    for (int i = 0; i < 16; ++i) {
        float acc = 0.0f;
#pragma unroll
        for (int k = 0; k < 8; ++k) {
            acc = fmaf(W0[k], wl[i + D * k], acc);
            acc = fmaf(W1[k], wh[i + D * k], acc);
        }
        res[i] = acc;
    }
}

static __device__ __forceinline__ void writeback(float* __restrict__ dst, int g0,
                                                 const float res[16])
{
#pragma unroll
    for (int j = 0; j < 4; ++j) {
        const int a = gaddr(g0 + j);
        *(float4*)(dst + a) = make_float4(res[4 * j + 0], res[4 * j + 1],
                                          res[4 * j + 2], res[4 * j + 3]);
    }
}

__global__ __launch_bounds__(256, 2)
void iswt_kernel(const float* __restrict__ in, float* __restrict__ out)
{
    __shared__ float lds[4][BANDF];   // 80 KB -> 2 blocks/CU

    const int tid  = threadIdx.x;
    const int row0 = blockIdx.x * RPB;

    float4 stage[16];
    {
        const float4* __restrict__ src = (const float4*)(in + (size_t)row0 * (T * 4));
#pragma unroll
        for (int j = 0; j < 16; ++j) stage[j] = src[tid + 256 * j];
    }

    for (int i = 0; i < RPB; ++i) {
        const int row = row0 + i;

        // ---- regs -> LDS (deinterleave 4 bands, padded) ----
#pragma unroll
        for (int j = 0; j < 16; ++j) {
            const int p = tid + 256 * j;
            const int a = p + ((p >> 4) << 2);
            lds[0][a] = stage[j].x;
            lds[1][a] = stage[j].y;
            lds[2][a] = stage[j].z;
            lds[3][a] = stage[j].w;
        }
        __syncthreads();

        // ---- issue next row's loads; they stay in flight under the compute ----
        if (i + 1 < RPB) {
            const float4* __restrict__ src = (const float4*)(in + (size_t)(row + 1) * (T * 4));
#pragma unroll
            for (int j = 0; j < 16; ++j) stage[j] = src[tid + 256 * j];
        }

        const int g0 = tid << 2;
        float res[16];

        // Level 1: lo = band3 (cD_1), hi = band2 (cD_2), dilation 4
        level<4, 11>(&lds[3][0], &lds[2][0], g0, res);
        __syncthreads();
        writeback(&lds[3][0], g0, res);
        __syncthreads();

        // Level 2: lo = res (buf3), hi = band1 (cD_3), dilation 2
        level<2, 8>(&lds[3][0], &lds[1][0], g0, res);
        __syncthreads();
        writeback(&lds[1][0], g0, res);
        __syncthreads();

        // Level 3: lo = res (buf1), hi = band0 (cA_3), dilation 1 -> global
        level<1, 6>(&lds[1][0], &lds[0][0], g0, res);

        float* __restrict__ o = out + (size_t)row * T + (tid << 4);
#pragma unroll
        for (int j = 0; j < 4; ++j)
            *(float4*)(o + 4 * j) = make_float4(res[4 * j + 0], res[4 * j + 1],
                                                res[4 * j + 2], res[4 * j + 3]);
        __syncthreads();   // protect LDS before next iteration's overwrite
    }
}

extern "C" void kernel_launch(void* const* d_in, const int* in_sizes, int n_in,
                              void* d_out, int out_size, void* d_ws, size_t ws_size,
                              hipStream_t stream)
{
    const float* coeffs = (const float*)d_in[0];
    float* out = (float*)d_out;
    const int nrows = in_sizes[0] / (T * 4);   // 4096
    iswt_kernel<<<nrows / RPB, 256, 0, stream>>>(coeffs, out);
}